// Round 14
// baseline (49.650 us; speedup 1.0000x reference)
//
#include <hip/hip_runtime.h>
#include <math.h>

typedef __attribute__((ext_vector_type(8))) _Float16 f16x8;
typedef __attribute__((ext_vector_type(2))) _Float16 f16x2;
typedef __attribute__((ext_vector_type(4))) float f32x4;

// ============================ MFMA fused kernel v12 ============================
// v12 vs v11 (42.1 µs):
//  1. STEP-SYNC BARRIER: W0/W1 are 64KB each > 32KB L1. All 4 waves read the
//     SAME B stream, but drift let the combined working set thrash L1 -> every
//     b-load went to L2 (~2MB/CU @ ~135GB/s = ~15us, the unattributed cost that
//     made every geometry change null). A raw s_barrier (no waitcnt drain) per
//     step keeps waves on the same 8KB chunk: 1 L2 miss + 3 L1 hits.
//  2. combine_w: 1024-thread blocks; bias via 8/16-way split + LDS reduce
//     (v11's 32-iter bias blocks were the straggler gating the mfma launch).

#define TPB 256
#define BM  128
#define HSTRIDE 272                    // 128 cols x 2B + 16B pad
#define LDS_TOT (128 * HSTRIDE)        // 34816 B

__global__ __launch_bounds__(TPB, 2) void kan_mfma_kernel(
    const float* __restrict__ x, const _Float16* __restrict__ W0t,
    const _Float16* __restrict__ W1t, const float* __restrict__ bias0,
    const float* __restrict__ bias1, float* __restrict__ out)
{
    __shared__ char smem[LDS_TOT];
    const int tid  = threadIdx.x;
    const int lane = tid & 63;
    const int wid  = tid >> 6;          // 4 waves, disjoint 32-row strips
    const int gq   = lane >> 4;         // k-group 0..3
    const int lm   = lane & 15;
    const int wavebase = wid * 32;
    const long rowbase = (long)blockIdx.x * BM;

#if __has_builtin(__builtin_amdgcn_cvt_pkrtz)
    auto pk2 = [](float a, float b) -> f16x2 {
        return (f16x2)__builtin_amdgcn_cvt_pkrtz(a, b);
    };
#else
    auto pk2 = [](float a, float b) -> f16x2 {
        return f16x2{(_Float16)a, (_Float16)b};
    };
#endif
#if __has_builtin(__builtin_amdgcn_rcpf)
    auto frcp = [](float a) -> float { return __builtin_amdgcn_rcpf(a); };
#else
    auto frcp = [](float a) -> float { return 1.0f / a; };
#endif

    // features for 8 values -> 4 fragments {base, gi, s1, s1*gi}
    auto buildFeats4 = [&](const float* v, f16x8* dst) {
        union U { f16x8 v8; f16x2 h2[4]; } u0, u1, u2, u3;
        #pragma unroll
        for (int q = 0; q < 4; ++q) {
            float va = v[2 * q], vb = v[2 * q + 1];
            float ba = va * frcp(1.0f + __expf(-va));
            float bb = vb * frcp(1.0f + __expf(-vb));
            float ga = fminf(fmaxf(va, -1.f), 1.f) + 1.f;   // [0,2]
            float gb = fminf(fmaxf(vb, -1.f), 1.f) + 1.f;
            float s1a = (ga >= 1.f) ? 1.f : 0.f;
            float s1b = (gb >= 1.f) ? 1.f : 0.f;
            float sga = (ga >= 1.f) ? ga : 0.f;
            float sgb = (gb >= 1.f) ? gb : 0.f;
            u0.h2[q] = pk2(ba, bb);
            u1.h2[q] = pk2(ga, gb);
            u2.h2[q] = pk2(s1a, s1b);
            u3.h2[q] = pk2(sga, sgb);
        }
        dst[0] = u0.v8; dst[1] = u1.v8; dst[2] = u2.v8; dst[3] = u3.v8;
    };

    // ---------------- bias fragments (per-column, fp32) ----------------
    float b0v[8], b1v[4];
    #pragma unroll
    for (int nf = 0; nf < 8; ++nf) b0v[nf] = bias0[nf * 16 + lm];
    #pragma unroll
    for (int nf = 0; nf < 4; ++nf) b1v[nf] = bias1[nf * 16 + lm];

    // ---------------- load x values for both i-halves ----------------
    float v0[2][8], v1[2][8];           // [mi][e]: ih=0 (i=gq*8..), ih=1 (i=32+gq*8..)
    #pragma unroll
    for (int mi = 0; mi < 2; ++mi) {
        const float* xp = x + (rowbase + wavebase + mi * 16 + lm) * 64 + gq * 8;
        float4 a0 = *(const float4*)(xp);
        float4 a1 = *(const float4*)(xp + 4);
        float4 a2 = *(const float4*)(xp + 32);
        float4 a3 = *(const float4*)(xp + 36);
        v0[mi][0]=a0.x; v0[mi][1]=a0.y; v0[mi][2]=a0.z; v0[mi][3]=a0.w;
        v0[mi][4]=a1.x; v0[mi][5]=a1.y; v0[mi][6]=a1.z; v0[mi][7]=a1.w;
        v1[mi][0]=a2.x; v1[mi][1]=a2.y; v1[mi][2]=a2.z; v1[mi][3]=a2.w;
        v1[mi][4]=a3.x; v1[mi][5]=a3.y; v1[mi][6]=a3.z; v1[mi][7]=a3.w;
    }

    // ---------------- layer 0: h[32 rows/wave][128 cols], 8 ih-major steps ----------------
    f32x4 acc[2][8] = {};
    {
        const char* w0 = (const char*)W0t + gq * 2048 + lm * 16;
        f16x8 b0[8], b1[8];
        #pragma unroll
        for (int nf = 0; nf < 8; ++nf) b0[nf] = *(const f16x8*)(w0 + nf * 256);

        f16x8 fr[2][4];
        buildFeats4(v0[0], fr[0]);
        buildFeats4(v0[1], fr[1]);

#define L0_STEP(S, C, CUR, NXT) do {                                          \
        if ((S) < 7) {                                                        \
            _Pragma("unroll")                                                 \
            for (int nf = 0; nf < 8; ++nf)                                    \
                NXT[nf] = *(const f16x8*)(w0 + ((S) + 1) * 8192 + nf * 256);  \
        }                                                                     \
        _Pragma("unroll")                                                     \
        for (int mi = 0; mi < 2; ++mi) {                                      \
            f16x8 a = fr[mi][C];                                              \
            _Pragma("unroll")                                                 \
            for (int nf = 0; nf < 8; ++nf)                                    \
                acc[mi][nf] = __builtin_amdgcn_mfma_f32_16x16x32_f16(         \
                    a, CUR[nf], acc[mi][nf], 0, 0, 0);                        \
        }                                                                     \
        __builtin_amdgcn_s_barrier();  /* keep waves on same W chunk (L1) */  \
    } while (0)

        L0_STEP(0, 0, b0, b1); L0_STEP(1, 1, b1, b0);
        L0_STEP(2, 2, b0, b1); L0_STEP(3, 3, b1, b0);
        buildFeats4(v1[0], fr[0]);
        buildFeats4(v1[1], fr[1]);
        L0_STEP(4, 0, b0, b1); L0_STEP(5, 1, b1, b0);
        L0_STEP(6, 2, b0, b1); L0_STEP(7, 3, b1, b0);
#undef L0_STEP
    }

    // h + bias0 -> H LDS f16 (C/D layout: row = gq*4+rg, col = nf*16+lm)
    #pragma unroll
    for (int mi = 0; mi < 2; ++mi)
        #pragma unroll
        for (int nf = 0; nf < 8; ++nf)
            #pragma unroll
            for (int rg = 0; rg < 4; ++rg)
                *(_Float16*)(smem + (wavebase + mi * 16 + gq * 4 + rg) * HSTRIDE
                             + (nf * 16 + lm) * 2) = (_Float16)(acc[mi][nf][rg] + b0v[nf]);
    __syncthreads();

    // ---------------- layer 1: out[32/wave][64], 2 halves x 8 ih-major steps ----------------
    f32x4 accO[2][4] = {};
    #pragma unroll
    for (int half = 0; half < 2; ++half) {
        float hv0[2][8], hv1[2][8];
        #pragma unroll
        for (int mi = 0; mi < 2; ++mi) {
            const char* hrow = smem + (wavebase + mi * 16 + lm) * HSTRIDE;
            f16x8 ha = *(const f16x8*)(hrow + (half * 64 + gq * 8) * 2);
            f16x8 hb = *(const f16x8*)(hrow + (half * 64 + 32 + gq * 8) * 2);
            #pragma unroll
            for (int e = 0; e < 8; ++e) { hv0[mi][e] = (float)ha[e]; hv1[mi][e] = (float)hb[e]; }
        }

        const char* w1 = (const char*)W1t + half * 32768 + gq * 1024 + lm * 16;
        f16x8 c0[4], c1[4];
        #pragma unroll
        for (int nf = 0; nf < 4; ++nf) c0[nf] = *(const f16x8*)(w1 + nf * 256);

        f16x8 fr[2][4];
        buildFeats4(hv0[0], fr[0]);
        buildFeats4(hv0[1], fr[1]);

#define L1_STEP(S, C, CUR, NXT) do {                                          \
        if ((S) < 7) {                                                        \
            _Pragma("unroll")                                                 \
            for (int nf = 0; nf < 4; ++nf)                                    \
                NXT[nf] = *(const f16x8*)(w1 + ((S) + 1) * 4096 + nf * 256);  \
        }                                                                     \
        _Pragma("unroll")                                                     \
        for (int mi = 0; mi < 2; ++mi) {                                      \
            f16x8 a = fr[mi][C];                                              \
            _Pragma("unroll")                                                 \
            for (int nf = 0; nf < 4; ++nf)                                    \
                accO[mi][nf] = __builtin_amdgcn_mfma_f32_16x16x32_f16(        \
                    a, CUR[nf], accO[mi][nf], 0, 0, 0);                       \
        }                                                                     \
        __builtin_amdgcn_s_barrier();                                         \
    } while (0)

        L1_STEP(0, 0, c0, c1); L1_STEP(1, 1, c1, c0);
        L1_STEP(2, 2, c0, c1); L1_STEP(3, 3, c1, c0);
        buildFeats4(hv1[0], fr[0]);
        buildFeats4(hv1[1], fr[1]);
        L1_STEP(4, 0, c0, c1); L1_STEP(5, 1, c1, c0);
        L1_STEP(6, 2, c0, c1); L1_STEP(7, 3, c1, c0);
#undef L1_STEP
    }

    // ---------------- store out (+bias1) ----------------
    float* og = out + (rowbase + wavebase) * 64;
    #pragma unroll
    for (int mi = 0; mi < 2; ++mi)
        #pragma unroll
        for (int nf = 0; nf < 4; ++nf)
            #pragma unroll
            for (int rg = 0; rg < 4; ++rg)
                og[(mi * 16 + gq * 4 + rg) * 64 + nf * 16 + lm] = accO[mi][nf][rg] + b1v[nf];
}

// ------------- pre-kernel: fold weights + fast parallel bias -------------
// 1024-thread blocks.  Blocks 0..63: weight fold (f = bx*1024+t, 65536 vals).
// Block 64: bias0 (128 j x 8-way i-split, 8 iters + LDS reduce).
// Block 65: bias1 (64 j x 16-way split).
// Feature order q: {base, gi, s1, s1*gi}.  Per edge:
//   P0 = cp.bv0 ; Q0 = cp.(bv1-bv0) ; P1 = cp.(2bv1-bv2) ; Q1 = cp.(bv2-bv1)
//   w = imp * {bw, sw*Q0, sw*(P1-P0), sw*(Q1-Q0)};  bias_j = sum_i imp*sw*P0
// W0t flat f = ((s*4+g)*128+n)*8+e ; s=ih*4+q ; i=ih*32+g*8+e ; edge=i*128+n
// W1t flat f = (((half*8+s)*4+g)*64+n)*8+e ; i2=half*64+ih*32+g*8+e
__global__ __launch_bounds__(1024) void kan_combine_w(
    const float* __restrict__ cp0, const float* __restrict__ bw0,
    const float* __restrict__ sw0, const float* __restrict__ imp0,
    const float* __restrict__ cp1, const float* __restrict__ bw1,
    const float* __restrict__ sw1, const float* __restrict__ imp1,
    _Float16* __restrict__ W0t, _Float16* __restrict__ W1t,
    float* __restrict__ bias0, float* __restrict__ bias1)
{
    float bvv[3][5];
    #pragma unroll
    for (int g = 0; g < 3; ++g) {
        float gv = (float)g - 1.0f;
        float e[5]; float s = 0.f;
        #pragma unroll
        for (int i = 0; i < 5; ++i) {
            float cc = -0.8125f + 0.325f * (float)i;
            float d  = (gv - cc) * (1.0f / 0.65f);
            e[i] = __expf(-d * d); s += e[i];
        }
        float inv = 1.0f / (s + 1e-6f);
        #pragma unroll
        for (int i = 0; i < 5; ++i) bvv[g][i] = e[i] * inv;
    }

    auto wval = [&](const float* cp, float bw, float sw, float imp, int q) -> float {
        if (q == 0) return imp * bw;
        float P0 = 0.f, Q0 = 0.f, P1 = 0.f, Q1 = 0.f;
        #pragma unroll
        for (int c = 0; c < 5; ++c) {
            P0 += cp[c] * bvv[0][c];
            Q0 += cp[c] * (bvv[1][c] - bvv[0][c]);
            P1 += cp[c] * (2.f * bvv[1][c] - bvv[2][c]);
            Q1 += cp[c] * (bvv[2][c] - bvv[1][c]);
        }
        float r = (q == 1) ? Q0 : (q == 2) ? (P1 - P0) : (Q1 - Q0);
        return imp * sw * r;
    };
    auto p0val = [&](const float* cp) -> float {
        float P0 = 0.f;
        #pragma unroll
        for (int c = 0; c < 5; ++c) P0 += cp[c] * bvv[0][c];
        return P0;
    };

    const int bx = blockIdx.x;
    const int t  = threadIdx.x;

    if (bx < 64) {
        int f = bx * 1024 + t;
        if (f < 32768) {
            int e = f & 7, n = (f >> 3) & 127, g = (f >> 10) & 3, s = f >> 12;
            int ih = s >> 2, q = s & 3;
            int i = ih * 32 + g * 8 + e;
            int edge = i * 128 + n;
            W0t[f] = (_Float16)wval(cp0 + edge * 5, bw0[edge], sw0[edge], imp0[edge], q);
        } else {
            int f2 = f - 32768;
            int e = f2 & 7, n = (f2 >> 3) & 63, g = (f2 >> 9) & 3;
            int tq = f2 >> 11;
            int half = tq >> 3, s = tq & 7;
            int ih = s >> 2, q = s & 3;
            int i2 = half * 64 + ih * 32 + g * 8 + e;
            int edge = i2 * 64 + n;
            W1t[f2] = (_Float16)wval(cp1 + edge * 5, bw1[edge], sw1[edge], imp1[edge], q);
        }
    } else if (bx == 64) {
        __shared__ float part[1024];
        int j = t >> 3, split = t & 7;           // 128 cols x 8 splits
        float s = 0.f;
        #pragma unroll
        for (int k = 0; k < 8; ++k) {
            int i = split * 8 + k;
            int edge = i * 128 + j;
            s += imp0[edge] * sw0[edge] * p0val(cp0 + edge * 5);
        }
        part[t] = s;
        __syncthreads();
        if (t < 128) {
            float acc = 0.f;
            #pragma unroll
            for (int k = 0; k < 8; ++k) acc += part[t * 8 + k];
            bias0[t] = acc;
        }
    } else {
        __shared__ float part[1024];
        int j = t >> 4, split = t & 15;          // 64 cols x 16 splits
        float s = 0.f;
        #pragma unroll
        for (int k = 0; k < 8; ++k) {
            int i2 = split * 8 + k;
            int edge = i2 * 64 + j;
            s += imp1[edge] * sw1[edge] * p0val(cp1 + edge * 5);
        }
        part[t] = s;
        __syncthreads();
        if (t < 64) {
            float acc = 0.f;
            #pragma unroll
            for (int k = 0; k < 16; ++k) acc += part[t * 16 + k];
            bias1[t] = acc;
        }
    }
}

// ===================== fallback: proven fp32 kernel (round 2) =====================
#define NTHR 256
#define JT 32
#define WS8 8

#define STAGE_L0(JBASE) do {                                                  \
    _Pragma("unroll")                                                         \
    for (int p = 0; p < 8; ++p) {                                             \
        int idx = tid + p * NTHR;                                             \
        int i  = idx >> 5;                                                    \
        int jj = idx & 31;                                                    \
        int e  = i * 128 + (JBASE) + jj;                                      \
        float im = imp0[e];                                                   \
        float wb = bw0[e] * im;                                               \
        float ws = sw0[e] * im;                                               \
        const float* cp = cp0 + e * 5;                                        \
        float* wp = wbuf + idx * WS8;                                         \
        wp[0] = wb;                                                           \
        wp[1] = ws * cp[0]; wp[2] = ws * cp[1]; wp[3] = ws * cp[2];           \
        wp[4] = ws * cp[3]; wp[5] = ws * cp[4];                               \
    }                                                                         \
} while (0)

#define STAGE_L1(IBASE, JBASE) do {                                           \
    _Pragma("unroll")                                                         \
    for (int p = 0; p < 8; ++p) {                                             \
        int idx = tid + p * NTHR;                                             \
        int ii = idx >> 5;                                                    \
        int jj = idx & 31;                                                    \
        int e  = ((IBASE) + ii) * 64 + (JBASE) + jj;                          \
        float im = imp1[e];                                                   \
        float wb = bw1[e] * im;                                               \
        float ws = sw1[e] * im;                                               \
        const float* cp = cp1 + e * 5;                                        \
        float* wp = wbuf + idx * WS8;                                         \
        wp[0] = wb;                                                           \
        wp[1] = ws * cp[0]; wp[2] = ws * cp[1]; wp[3] = ws * cp[2];           \
        wp[4] = ws * cp[3]; wp[5] = ws * cp[4];                               \
    }                                                                         \
} while (0)

#define COMPUTE_TILE(ACC) do {                                                \
    _Pragma("unroll 2")                                                       \
    for (int i = 0; i < 64; ++i) {                                            \
        float v  = vbuf[i][tid];                                              \
        float sg = 1.0f / (1.0f + __expf(-v));                                \
        float base = v * sg;                                                  \
        float xc = fminf(fmaxf(v, -1.0f), 1.0f);                              \
        float gi = xc + 1.0f;                                                 \
        int lo = (int)gi; lo = (lo > 2) ? 2 : lo;                             \
        float fr = gi - (float)lo;                                            \
        int hi = (fr > 0.0f) ? (lo + 1) : lo;                                 \
        float b0 = bvt[lo][0]; b0 += (bvt[hi][0] - b0) * fr;                  \
        float b1 = bvt[lo][1]; b1 += (bvt[hi][1] - b1) * fr;                  \
        float b2 = bvt[lo][2]; b2 += (bvt[hi][2] - b2) * fr;                  \
        float b3 = bvt[lo][3]; b3 += (bvt[hi][3] - b3) * fr;                  \
        float b4 = bvt[lo][4]; b4 += (bvt[hi][4] - b4) * fr;                  \
        const float* wr = wbuf + i * (JT * WS8);                              \
        _Pragma("unroll")                                                     \
        for (int jj = 0; jj < JT; ++jj) {                                     \
            const float* wp = wr + jj * WS8;                                  \
            float a = ACC[jj];                                                \
            a = fmaf(wp[0], base, a);                                         \
            a = fmaf(wp[1], b0, a);                                           \
            a = fmaf(wp[2], b1, a);                                           \
            a = fmaf(wp[3], b2, a);                                           \
            a = fmaf(wp[4], b3, a);                                           \
            a = fmaf(wp[5], b4, a);                                           \
            ACC[jj] = a;                                                      \
        }                                                                     \
    }                                                                         \
} while (0)

__global__ __launch_bounds__(NTHR) void kan_fused_kernel(
    const float* __restrict__ x,
    const float* __restrict__ cp0, const float* __restrict__ bw0,
    const float* __restrict__ sw0, const float* __restrict__ imp0,
    const float* __restrict__ cp1, const float* __restrict__ bw1,
    const float* __restrict__ sw1, const float* __restrict__ imp1,
    float* __restrict__ out)
{
    __shared__ float vbuf[64][NTHR + 1];
    __shared__ float wbuf[64 * JT * WS8];
    __shared__ float bvt[3][8];

    const int tid = threadIdx.x;

    if (tid < 3) {
        float gv = -1.0f + (float)tid;
        float e[5];
        float s = 0.0f;
        #pragma unroll
        for (int i = 0; i < 5; ++i) {
            float c = -0.8125f + 0.325f * (float)i;
            float d = (gv - c) * (1.0f / 0.65f);
            e[i] = expf(-d * d);
            s += e[i];
        }
        float inv = 1.0f / (s + 1e-6f);
        #pragma unroll
        for (int i = 0; i < 5; ++i) bvt[tid][i] = e[i] * inv;
    }

    {
        const float4* xg = (const float4*)(x + (size_t)blockIdx.x * (NTHR * 64));
        #pragma unroll
        for (int it = 0; it < 16; ++it) {
            int e4 = tid + it * NTHR;
            float4 v = xg[e4];
            int r  = e4 >> 4;
            int ib = (e4 & 15) << 2;
            vbuf[ib + 0][r] = v.x;
            vbuf[ib + 1][r] = v.y;
            vbuf[ib + 2][r] = v.z;
            vbuf[ib + 3][r] = v.w;
        }
    }
    __syncthreads();

    float h0[32] = {}, h1[32] = {}, h2[32] = {}, h3[32] = {};
    STAGE_L0(0);   __syncthreads(); COMPUTE_TILE(h0); __syncthreads();
    STAGE_L0(32);  __syncthreads(); COMPUTE_TILE(h1); __syncthreads();
    STAGE_L0(64);  __syncthreads(); COMPUTE_TILE(h2); __syncthreads();
    STAGE_L0(96);  __syncthreads(); COMPUTE_TILE(h3); __syncthreads();

    #pragma unroll
    for (int i = 0; i < 32; ++i) vbuf[i][tid] = h0[i];
    #pragma unroll
    for (int i = 0; i < 32; ++i) vbuf[32 + i][tid] = h1[i];

    float o0[32] = {}, o1[32] = {};
    STAGE_L1(0, 0);   __syncthreads(); COMPUTE_TILE(o0); __syncthreads();
    STAGE_L1(0, 32);  __syncthreads(); COMPUTE_TILE(o1); __syncthreads();

    #pragma unroll
    for (int i = 0; i < 32; ++i) vbuf[i][tid] = h2[i];
    #pragma unroll
    for (int i = 0; i < 32; ++i) vbuf[32 + i][tid] = h3[i];

    STAGE_L1(64, 0);  __syncthreads(); COMPUTE_TILE(o0); __syncthreads();
    STAGE_L1(64, 32); __syncthreads(); COMPUTE_TILE(o1);

    float4* og = (float4*)(out + (size_t)blockIdx.x * (NTHR * 64) + (size_t)tid * 64);
    #pragma unroll
    for (int q = 0; q < 8; ++q)
        og[q] = make_float4(o0[4 * q + 0], o0[4 * q + 1], o0[4 * q + 2], o0[4 * q + 3]);
    #pragma unroll
    for (int q = 0; q < 8; ++q)
        og[8 + q] = make_float4(o1[4 * q + 0], o1[4 * q + 1], o1[4 * q + 2], o1[4 * q + 3]);
}

// =================================== launch ===================================
extern "C" void kernel_launch(void* const* d_in, const int* in_sizes, int n_in,
                              void* d_out, int out_size, void* d_ws, size_t ws_size,
                              hipStream_t stream) {
    const float* x    = (const float*)d_in[0];
    const float* cp0  = (const float*)d_in[1];
    const float* bw0  = (const float*)d_in[2];
    const float* sw0  = (const float*)d_in[3];
    const float* imp0 = (const float*)d_in[4];
    const float* cp1  = (const float*)d_in[5];
    const float* bw1  = (const float*)d_in[6];
    const float* sw1  = (const float*)d_in[7];
    const float* imp1 = (const float*)d_in[8];
    float* out = (float*)d_out;

    const int B = in_sizes[0] / 64;                 // 131072
    const size_t need = 65536 * sizeof(_Float16) + 192 * sizeof(float);

    if (ws_size >= need && (B % BM) == 0) {
        _Float16* W0t = (_Float16*)d_ws;
        _Float16* W1t = W0t + 32768;
        float* bias0 = (float*)(W1t + 32768);
        float* bias1 = bias0 + 128;
        kan_combine_w<<<66, 1024, 0, stream>>>(cp0, bw0, sw0, imp0,
                                               cp1, bw1, sw1, imp1,
                                               W0t, W1t, bias0, bias1);
        kan_mfma_kernel<<<B / BM, TPB, 0, stream>>>(x, W0t, W1t, bias0, bias1, out);
    } else {
        kan_fused_kernel<<<B / NTHR, NTHR, 0, stream>>>(
            x, cp0, bw0, sw0, imp0, cp1, bw1, sw1, imp1, out);
    }
}

// Round 15
// 37.576 us; speedup vs baseline: 1.3213x; 1.3213x over previous
//
#include <hip/hip_runtime.h>
#include <math.h>

typedef __attribute__((ext_vector_type(8))) _Float16 f16x8;
typedef __attribute__((ext_vector_type(2))) _Float16 f16x2;
typedef __attribute__((ext_vector_type(4))) float f32x4;

// ============================ MFMA fused kernel v13 ============================
// v13 vs v12 (49.6, s_barrier regression reverted) / v11 (42.1):
//  T14 ASYNC W-STAGING THROUGH LDS: v11's register "double buffer" was collapsed
//  by the compiler (VGPR=84 proves it), so each of 4 waves separately streamed
//  128KB of W with exposed ~200cy latency per load -- the invariant ~37us.
//  Now each W chunk (8KB L0 / 4KB L1) is staged ONCE PER BLOCK: global loads
//  issued BEFORE the step's compute (latency hidden under MFMA+VALU+ds_read),
//  ds_write to the alternate buffer AFTER, one __syncthreads per step.
//  B-fragments come from LDS ds_read_b128 (conflict-free layout).
//  LDS = H(34816) + 2x8192 = 51200 -> 3 blocks/CU.
//  combine_w: bias spread over 32 blocks (2-iter loops, no straggler).

#define TPB 256
#define BM  128
#define HSTRIDE 272                    // 128 cols x 2B + 16B pad
#define W_OFF   34816                  // H bytes
#define LDS_TOT (34816 + 16384)        // 51200 B

__global__ __launch_bounds__(TPB, 2) void kan_mfma_kernel(
    const float* __restrict__ x, const _Float16* __restrict__ W0t,
    const _Float16* __restrict__ W1t, const float* __restrict__ bias0,
    const float* __restrict__ bias1, float* __restrict__ out)
{
    __shared__ char smem[LDS_TOT];
    const int tid  = threadIdx.x;
    const int lane = tid & 63;
    const int wid  = tid >> 6;          // 4 waves, disjoint 32-row strips
    const int gq   = lane >> 4;         // k-group 0..3
    const int lm   = lane & 15;
    const int wavebase = wid * 32;
    const long rowbase = (long)blockIdx.x * BM;

#if __has_builtin(__builtin_amdgcn_cvt_pkrtz)
    auto pk2 = [](float a, float b) -> f16x2 {
        return (f16x2)__builtin_amdgcn_cvt_pkrtz(a, b);
    };
#else
    auto pk2 = [](float a, float b) -> f16x2 {
        return f16x2{(_Float16)a, (_Float16)b};
    };
#endif
#if __has_builtin(__builtin_amdgcn_rcpf)
    auto frcp = [](float a) -> float { return __builtin_amdgcn_rcpf(a); };
#else
    auto frcp = [](float a) -> float { return 1.0f / a; };
#endif

    // features for 8 values -> 4 fragments {base, gi, s1, s1*gi}
    auto buildFeats4 = [&](const float* v, f16x8* dst) {
        union U { f16x8 v8; f16x2 h2[4]; } u0, u1, u2, u3;
        #pragma unroll
        for (int q = 0; q < 4; ++q) {
            float va = v[2 * q], vb = v[2 * q + 1];
            float ba = va * frcp(1.0f + __expf(-va));
            float bb = vb * frcp(1.0f + __expf(-vb));
            float ga = fminf(fmaxf(va, -1.f), 1.f) + 1.f;   // [0,2]
            float gb = fminf(fmaxf(vb, -1.f), 1.f) + 1.f;
            float s1a = (ga >= 1.f) ? 1.f : 0.f;
            float s1b = (gb >= 1.f) ? 1.f : 0.f;
            float sga = (ga >= 1.f) ? ga : 0.f;
            float sgb = (gb >= 1.f) ? gb : 0.f;
            u0.h2[q] = pk2(ba, bb);
            u1.h2[q] = pk2(ga, gb);
            u2.h2[q] = pk2(s1a, s1b);
            u3.h2[q] = pk2(sga, sgb);
        }
        dst[0] = u0.v8; dst[1] = u1.v8; dst[2] = u2.v8; dst[3] = u3.v8;
    };

    // ---------------- bias fragments (per-column, fp32) ----------------
    float b0v[8], b1v[4];
    #pragma unroll
    for (int nf = 0; nf < 8; ++nf) b0v[nf] = bias0[nf * 16 + lm];
    #pragma unroll
    for (int nf = 0; nf < 4; ++nf) b1v[nf] = bias1[nf * 16 + lm];

    // ---------------- load x values for both i-halves ----------------
    float v0[2][8], v1[2][8];           // [mi][e]: ih=0 (i=gq*8..), ih=1 (i=32+gq*8..)
    #pragma unroll
    for (int mi = 0; mi < 2; ++mi) {
        const float* xp = x + (rowbase + wavebase + mi * 16 + lm) * 64 + gq * 8;
        float4 a0 = *(const float4*)(xp);
        float4 a1 = *(const float4*)(xp + 4);
        float4 a2 = *(const float4*)(xp + 32);
        float4 a3 = *(const float4*)(xp + 36);
        v0[mi][0]=a0.x; v0[mi][1]=a0.y; v0[mi][2]=a0.z; v0[mi][3]=a0.w;
        v0[mi][4]=a1.x; v0[mi][5]=a1.y; v0[mi][6]=a1.z; v0[mi][7]=a1.w;
        v1[mi][0]=a2.x; v1[mi][1]=a2.y; v1[mi][2]=a2.z; v1[mi][3]=a2.w;
        v1[mi][4]=a3.x; v1[mi][5]=a3.y; v1[mi][6]=a3.z; v1[mi][7]=a3.w;
    }

    // ---------------- layer 0: 8 steps, W staged 8KB/step through LDS ----------------
    f32x4 acc[2][8] = {};
    {
        const char* w0 = (const char*)W0t;
        const int lb0 = (gq * 128 + lm) * 16;    // + nf*256 within chunk

        // prologue: stage chunk 0
        {
            float4 pa = *(const float4*)(w0 + tid * 32);
            float4 pb = *(const float4*)(w0 + tid * 32 + 16);
            *(float4*)(smem + W_OFF + tid * 32)      = pa;
            *(float4*)(smem + W_OFF + tid * 32 + 16) = pb;
        }
        f16x8 fr[2][4];
        buildFeats4(v0[0], fr[0]);
        buildFeats4(v0[1], fr[1]);
        __syncthreads();

        float4 wr0, wr1;
#define L0_STEP(S, C) do {                                                    \
        if ((S) < 7) {                                                        \
            wr0 = *(const float4*)(w0 + ((S) + 1) * 8192 + tid * 32);         \
            wr1 = *(const float4*)(w0 + ((S) + 1) * 8192 + tid * 32 + 16);    \
        }                                                                     \
        const char* wb = smem + W_OFF + ((S) & 1) * 8192;                     \
        f16x8 bt[8];                                                          \
        _Pragma("unroll")                                                     \
        for (int nf = 0; nf < 8; ++nf)                                        \
            bt[nf] = *(const f16x8*)(wb + lb0 + nf * 256);                    \
        _Pragma("unroll")                                                     \
        for (int mi = 0; mi < 2; ++mi) {                                      \
            f16x8 a = fr[mi][C];                                              \
            _Pragma("unroll")                                                 \
            for (int nf = 0; nf < 8; ++nf)                                    \
                acc[mi][nf] = __builtin_amdgcn_mfma_f32_16x16x32_f16(         \
                    a, bt[nf], acc[mi][nf], 0, 0, 0);                         \
        }                                                                     \
        if ((S) < 7) {                                                        \
            char* nb = smem + W_OFF + (((S) + 1) & 1) * 8192;                 \
            *(float4*)(nb + tid * 32)      = wr0;                             \
            *(float4*)(nb + tid * 32 + 16) = wr1;                             \
        }                                                                     \
        __syncthreads();                                                      \
    } while (0)

        L0_STEP(0, 0); L0_STEP(1, 1); L0_STEP(2, 2); L0_STEP(3, 3);
        buildFeats4(v1[0], fr[0]);
        buildFeats4(v1[1], fr[1]);
        L0_STEP(4, 0); L0_STEP(5, 1); L0_STEP(6, 2); L0_STEP(7, 3);
#undef L0_STEP
    }

    // h + bias0 -> H LDS f16 ; prologue-stage L1 chunk 0 (loads issued early)
    {
        const char* w1 = (const char*)W1t;
        float4 p0 = *(const float4*)(w1 + tid * 16);    // L1 chunk0 (4KB)
        #pragma unroll
        for (int mi = 0; mi < 2; ++mi)
            #pragma unroll
            for (int nf = 0; nf < 8; ++nf)
                #pragma unroll
                for (int rg = 0; rg < 4; ++rg)
                    *(_Float16*)(smem + (wavebase + mi * 16 + gq * 4 + rg) * HSTRIDE
                                 + (nf * 16 + lm) * 2) = (_Float16)(acc[mi][nf][rg] + b0v[nf]);
        __syncthreads();                 // H visible; L0 W-buffer reads all done
        *(float4*)(smem + W_OFF + tid * 16) = p0;
        __syncthreads();                 // L1 chunk0 staged
    }

    // ---------------- layer 1: 16 steps (2 halves x 8), 4KB chunks ----------------
    f32x4 accO[2][4] = {};
    {
        const char* w1 = (const char*)W1t;
        const int lb1 = (gq * 64 + lm) * 16;     // + nf*256 within chunk
        f16x8 fr[2][4];
        float4 wr0;

#define L1_STEP(CI, C) do {                                                   \
        if ((CI) < 15)                                                        \
            wr0 = *(const float4*)(w1 + ((CI) + 1) * 4096 + tid * 16);        \
        const char* wb = smem + W_OFF + ((CI) & 1) * 8192;                    \
        f16x8 bt[4];                                                          \
        _Pragma("unroll")                                                     \
        for (int nf = 0; nf < 4; ++nf)                                        \
            bt[nf] = *(const f16x8*)(wb + lb1 + nf * 256);                    \
        _Pragma("unroll")                                                     \
        for (int mi = 0; mi < 2; ++mi) {                                      \
            f16x8 a = fr[mi][C];                                              \
            _Pragma("unroll")                                                 \
            for (int nf = 0; nf < 4; ++nf)                                    \
                accO[mi][nf] = __builtin_amdgcn_mfma_f32_16x16x32_f16(        \
                    a, bt[nf], accO[mi][nf], 0, 0, 0);                        \
        }                                                                     \
        if ((CI) < 15)                                                        \
            *(float4*)(smem + W_OFF + (((CI) + 1) & 1) * 8192 + tid * 16) = wr0; \
        __syncthreads();                                                      \
    } while (0)

#define L1_FEATS(HALF, IH) do {                                               \
        _Pragma("unroll")                                                     \
        for (int mi = 0; mi < 2; ++mi) {                                      \
            const char* hrow = smem + (wavebase + mi * 16 + lm) * HSTRIDE;    \
            f16x8 hv = *(const f16x8*)(hrow + ((HALF) * 64 + (IH) * 32 + gq * 8) * 2); \
            float v[8];                                                       \
            _Pragma("unroll")                                                 \
            for (int e = 0; e < 8; ++e) v[e] = (float)hv[e];                  \
            buildFeats4(v, fr[mi]);                                           \
        }                                                                     \
    } while (0)

        L1_FEATS(0, 0);
        L1_STEP(0, 0);  L1_STEP(1, 1);  L1_STEP(2, 2);  L1_STEP(3, 3);
        L1_FEATS(0, 1);
        L1_STEP(4, 0);  L1_STEP(5, 1);  L1_STEP(6, 2);  L1_STEP(7, 3);
        L1_FEATS(1, 0);
        L1_STEP(8, 0);  L1_STEP(9, 1);  L1_STEP(10, 2); L1_STEP(11, 3);
        L1_FEATS(1, 1);
        L1_STEP(12, 0); L1_STEP(13, 1); L1_STEP(14, 2); L1_STEP(15, 3);
#undef L1_STEP
#undef L1_FEATS
    }

    // ---------------- store out (+bias1) ----------------
    float* og = out + (rowbase + wavebase) * 64;
    #pragma unroll
    for (int mi = 0; mi < 2; ++mi)
        #pragma unroll
        for (int nf = 0; nf < 4; ++nf)
            #pragma unroll
            for (int rg = 0; rg < 4; ++rg)
                og[(mi * 16 + gq * 4 + rg) * 64 + nf * 16 + lm] = accO[mi][nf][rg] + b1v[nf];
}

// ------------- pre-kernel: fold weights + wide-parallel bias -------------
// blocks 0..255: weight fold.  blocks 256..271: bias0 (16 blk x 8 cols, 2-iter).
// blocks 272..287: bias1 (16 blk x 4 cols, 2-iter).
// Feature order q: {base, gi, s1, s1*gi}.  Per edge:
//   P0 = cp.bv0 ; Q0 = cp.(bv1-bv0) ; P1 = cp.(2bv1-bv2) ; Q1 = cp.(bv2-bv1)
//   w = imp * {bw, sw*Q0, sw*(P1-P0), sw*(Q1-Q0)};  bias_j = sum_i imp*sw*P0
// W0t flat f = ((s*4+g)*128+n)*8+e ; s=ih*4+q ; i=ih*32+g*8+e ; edge=i*128+n
// W1t flat f = (((half*8+s)*4+g)*64+n)*8+e ; i2=half*64+ih*32+g*8+e
__global__ __launch_bounds__(256) void kan_combine_w(
    const float* __restrict__ cp0, const float* __restrict__ bw0,
    const float* __restrict__ sw0, const float* __restrict__ imp0,
    const float* __restrict__ cp1, const float* __restrict__ bw1,
    const float* __restrict__ sw1, const float* __restrict__ imp1,
    _Float16* __restrict__ W0t, _Float16* __restrict__ W1t,
    float* __restrict__ bias0, float* __restrict__ bias1)
{
    float bvv[3][5];
    #pragma unroll
    for (int g = 0; g < 3; ++g) {
        float gv = (float)g - 1.0f;
        float e[5]; float s = 0.f;
        #pragma unroll
        for (int i = 0; i < 5; ++i) {
            float cc = -0.8125f + 0.325f * (float)i;
            float d  = (gv - cc) * (1.0f / 0.65f);
            e[i] = __expf(-d * d); s += e[i];
        }
        float inv = 1.0f / (s + 1e-6f);
        #pragma unroll
        for (int i = 0; i < 5; ++i) bvv[g][i] = e[i] * inv;
    }

    auto wval = [&](const float* cp, float bw, float sw, float imp, int q) -> float {
        if (q == 0) return imp * bw;
        float P0 = 0.f, Q0 = 0.f, P1 = 0.f, Q1 = 0.f;
        #pragma unroll
        for (int c = 0; c < 5; ++c) {
            P0 += cp[c] * bvv[0][c];
            Q0 += cp[c] * (bvv[1][c] - bvv[0][c]);
            P1 += cp[c] * (2.f * bvv[1][c] - bvv[2][c]);
            Q1 += cp[c] * (bvv[2][c] - bvv[1][c]);
        }
        float r = (q == 1) ? Q0 : (q == 2) ? (P1 - P0) : (Q1 - Q0);
        return imp * sw * r;
    };
    auto p0val = [&](const float* cp) -> float {
        float P0 = 0.f;
        #pragma unroll
        for (int c = 0; c < 5; ++c) P0 += cp[c] * bvv[0][c];
        return P0;
    };

    const int bx = blockIdx.x;
    const int t  = threadIdx.x;

    if (bx < 256) {
        int f = bx * 256 + t;
        if (f < 32768) {
            int e = f & 7, n = (f >> 3) & 127, g = (f >> 10) & 3, s = f >> 12;
            int ih = s >> 2, q = s & 3;
            int i = ih * 32 + g * 8 + e;
            int edge = i * 128 + n;
            W0t[f] = (_Float16)wval(cp0 + edge * 5, bw0[edge], sw0[edge], imp0[edge], q);
        } else {
            int f2 = f - 32768;
            int e = f2 & 7, n = (f2 >> 3) & 63, g = (f2 >> 9) & 3;
            int tq = f2 >> 11;
            int half = tq >> 3, s = tq & 7;
            int ih = s >> 2, q = s & 3;
            int i2 = half * 64 + ih * 32 + g * 8 + e;
            int edge = i2 * 64 + n;
            W1t[f2] = (_Float16)wval(cp1 + edge * 5, bw1[edge], sw1[edge], imp1[edge], q);
        }
    } else if (bx < 272) {
        // bias0: 16 blocks x 8 cols; 32 splits x 2 i's per col
        __shared__ float part[256];
        int bb = bx - 256;
        int jj = t >> 5, split = t & 31;
        int j = bb * 8 + jj;
        float s = 0.f;
        #pragma unroll
        for (int k = 0; k < 2; ++k) {
            int i = split * 2 + k;
            int edge = i * 128 + j;
            s += imp0[edge] * sw0[edge] * p0val(cp0 + edge * 5);
        }
        part[t] = s;
        __syncthreads();
        if (t < 8) {
            float acc = 0.f;
            #pragma unroll
            for (int k = 0; k < 32; ++k) acc += part[t * 32 + k];
            bias0[bb * 8 + t] = acc;
        }
    } else {
        // bias1: 16 blocks x 4 cols; 64 splits x 2 i2's per col
        __shared__ float part[256];
        int bb = bx - 272;
        int jj = t >> 6, split = t & 63;
        int j = bb * 4 + jj;
        float s = 0.f;
        #pragma unroll
        for (int k = 0; k < 2; ++k) {
            int i2 = split * 2 + k;
            int edge = i2 * 64 + j;
            s += imp1[edge] * sw1[edge] * p0val(cp1 + edge * 5);
        }
        part[t] = s;
        __syncthreads();
        if (t < 4) {
            float acc = 0.f;
            #pragma unroll
            for (int k = 0; k < 64; ++k) acc += part[t * 64 + k];
            bias1[bb * 4 + t] = acc;
        }
    }
}

// ===================== fallback: proven fp32 kernel (round 2) =====================
#define NTHR 256
#define JT 32
#define WS8 8

#define STAGE_L0(JBASE) do {                                                  \
    _Pragma("unroll")                                                         \
    for (int p = 0; p < 8; ++p) {                                             \
        int idx = tid + p * NTHR;                                             \
        int i  = idx >> 5;                                                    \
        int jj = idx & 31;                                                    \
        int e  = i * 128 + (JBASE) + jj;                                      \
        float im = imp0[e];                                                   \
        float wb = bw0[e] * im;                                               \
        float ws = sw0[e] * im;                                               \
        const float* cp = cp0 + e * 5;                                        \
        float* wp = wbuf + idx * WS8;                                         \
        wp[0] = wb;                                                           \
        wp[1] = ws * cp[0]; wp[2] = ws * cp[1]; wp[3] = ws * cp[2];           \
        wp[4] = ws * cp[3]; wp[5] = ws * cp[4];                               \
    }                                                                         \
} while (0)

#define STAGE_L1(IBASE, JBASE) do {                                           \
    _Pragma("unroll")                                                         \
    for (int p = 0; p < 8; ++p) {                                             \
        int idx = tid + p * NTHR;                                             \
        int ii = idx >> 5;                                                    \
        int jj = idx & 31;                                                    \
        int e  = ((IBASE) + ii) * 64 + (JBASE) + jj;                          \
        float im = imp1[e];                                                   \
        float wb = bw1[e] * im;                                               \
        float ws = sw1[e] * im;                                               \
        const float* cp = cp1 + e * 5;                                        \
        float* wp = wbuf + idx * WS8;                                         \
        wp[0] = wb;                                                           \
        wp[1] = ws * cp[0]; wp[2] = ws * cp[1]; wp[3] = ws * cp[2];           \
        wp[4] = ws * cp[3]; wp[5] = ws * cp[4];                               \
    }                                                                         \
} while (0)

#define COMPUTE_TILE(ACC) do {                                                \
    _Pragma("unroll 2")                                                       \
    for (int i = 0; i < 64; ++i) {                                            \
        float v  = vbuf[i][tid];                                              \
        float sg = 1.0f / (1.0f + __expf(-v));                                \
        float base = v * sg;                                                  \
        float xc = fminf(fmaxf(v, -1.0f), 1.0f);                              \
        float gi = xc + 1.0f;                                                 \
        int lo = (int)gi; lo = (lo > 2) ? 2 : lo;                             \
        float fr = gi - (float)lo;                                            \
        int hi = (fr > 0.0f) ? (lo + 1) : lo;                                 \
        float b0 = bvt[lo][0]; b0 += (bvt[hi][0] - b0) * fr;                  \
        float b1 = bvt[lo][1]; b1 += (bvt[hi][1] - b1) * fr;                  \
        float b2 = bvt[lo][2]; b2 += (bvt[hi][2] - b2) * fr;                  \
        float b3 = bvt[lo][3]; b3 += (bvt[hi][3] - b3) * fr;                  \
        float b4 = bvt[lo][4]; b4 += (bvt[hi][4] - b4) * fr;                  \
        const float* wr = wbuf + i * (JT * WS8);                              \
        _Pragma("unroll")                                                     \
        for (int jj = 0; jj < JT; ++jj) {                                     \
            const float* wp = wr + jj * WS8;                                  \
            float a = ACC[jj];                                                \
            a = fmaf(wp[0], base, a);                                         \
            a = fmaf(wp[1], b0, a);                                           \
            a = fmaf(wp[2], b1, a);                                           \
            a = fmaf(wp[3], b2, a);                                           \
            a = fmaf(wp[4], b3, a);                                           \
            a = fmaf(wp[5], b4, a);                                           \
            ACC[jj] = a;                                                      \
        }                                                                     \
    }                                                                         \
} while (0)

__global__ __launch_bounds__(NTHR) void kan_fused_kernel(
    const float* __restrict__ x,
    const float* __restrict__ cp0, const float* __restrict__ bw0,
    const float* __restrict__ sw0, const float* __restrict__ imp0,
    const float* __restrict__ cp1, const float* __restrict__ bw1,
    const float* __restrict__ sw1, const float* __restrict__ imp1,
    float* __restrict__ out)
{
    __shared__ float vbuf[64][NTHR + 1];
    __shared__ float wbuf[64 * JT * WS8];
    __shared__ float bvt[3][8];

    const int tid = threadIdx.x;

    if (tid < 3) {
        float gv = -1.0f + (float)tid;
        float e[5];
        float s = 0.0f;
        #pragma unroll
        for (int i = 0; i < 5; ++i) {
            float c = -0.8125f + 0.325f * (float)i;
            float d = (gv - c) * (1.0f / 0.65f);
            e[i] = expf(-d * d);
            s += e[i];
        }
        float inv = 1.0f / (s + 1e-6f);
        #pragma unroll
        for (int i = 0; i < 5; ++i) bvt[tid][i] = e[i] * inv;
    }

    {
        const float4* xg = (const float4*)(x + (size_t)blockIdx.x * (NTHR * 64));
        #pragma unroll
        for (int it = 0; it < 16; ++it) {
            int e4 = tid + it * NTHR;
            float4 v = xg[e4];
            int r  = e4 >> 4;
            int ib = (e4 & 15) << 2;
            vbuf[ib + 0][r] = v.x;
            vbuf[ib + 1][r] = v.y;
            vbuf[ib + 2][r] = v.z;
            vbuf[ib + 3][r] = v.w;
        }
    }
    __syncthreads();

    float h0[32] = {}, h1[32] = {}, h2[32] = {}, h3[32] = {};
    STAGE_L0(0);   __syncthreads(); COMPUTE_TILE(h0); __syncthreads();
    STAGE_L0(32);  __syncthreads(); COMPUTE_TILE(h1); __syncthreads();
    STAGE_L0(64);  __syncthreads(); COMPUTE_TILE(h2); __syncthreads();
    STAGE_L0(96);  __syncthreads(); COMPUTE_TILE(h3); __syncthreads();

    #pragma unroll
    for (int i = 0; i < 32; ++i) vbuf[i][tid] = h0[i];
    #pragma unroll
    for (int i = 0; i < 32; ++i) vbuf[32 + i][tid] = h1[i];

    float o0[32] = {}, o1[32] = {};
    STAGE_L1(0, 0);   __syncthreads(); COMPUTE_TILE(o0); __syncthreads();
    STAGE_L1(0, 32);  __syncthreads(); COMPUTE_TILE(o1); __syncthreads();

    #pragma unroll
    for (int i = 0; i < 32; ++i) vbuf[i][tid] = h2[i];
    #pragma unroll
    for (int i = 0; i < 32; ++i) vbuf[32 + i][tid] = h3[i];

    STAGE_L1(64, 0);  __syncthreads(); COMPUTE_TILE(o0); __syncthreads();
    STAGE_L1(64, 32); __syncthreads(); COMPUTE_TILE(o1);

    float4* og = (float4*)(out + (size_t)blockIdx.x * (NTHR * 64) + (size_t)tid * 64);
    #pragma unroll
    for (int q = 0; q < 8; ++q)
        og[q] = make_float4(o0[4 * q + 0], o0[4 * q + 1], o0[4 * q + 2], o0[4 * q + 3]);
    #pragma unroll
    for (int q = 0; q < 8; ++q)
        og[8 + q] = make_float4(o1[4 * q + 0], o1[4 * q + 1], o1[4 * q + 2], o1[4 * q + 3]);
}

// =================================== launch ===================================
extern "C" void kernel_launch(void* const* d_in, const int* in_sizes, int n_in,
                              void* d_out, int out_size, void* d_ws, size_t ws_size,
                              hipStream_t stream) {
    const float* x    = (const float*)d_in[0];
    const float* cp0  = (const float*)d_in[1];
    const float* bw0  = (const float*)d_in[2];
    const float* sw0  = (const float*)d_in[3];
    const float* imp0 = (const float*)d_in[4];
    const float* cp1  = (const float*)d_in[5];
    const float* bw1  = (const float*)d_in[6];
    const float* sw1  = (const float*)d_in[7];
    const float* imp1 = (const float*)d_in[8];
    float* out = (float*)d_out;

    const int B = in_sizes[0] / 64;                 // 131072
    const size_t need = 65536 * sizeof(_Float16) + 192 * sizeof(float);

    if (ws_size >= need && (B % BM) == 0) {
        _Float16* W0t = (_Float16*)d_ws;
        _Float16* W1t = W0t + 32768;
        float* bias0 = (float*)(W1t + 32768);
        float* bias1 = bias0 + 128;
        kan_combine_w<<<288, 256, 0, stream>>>(cp0, bw0, sw0, imp0,
                                               cp1, bw1, sw1, imp1,
                                               W0t, W1t, bias0, bias1);
        kan_mfma_kernel<<<B / BM, TPB, 0, stream>>>(x, W0t, W1t, bias0, bias1, out);
    } else {
        kan_fused_kernel<<<B / NTHR, NTHR, 0, stream>>>(
            x, cp0, bw0, sw0, imp0, cp1, bw1, sw1, imp1, out);
    }
}

// Round 16
// 37.404 us; speedup vs baseline: 1.3274x; 1.0046x over previous
//
#include <hip/hip_runtime.h>
#include <math.h>

typedef __attribute__((ext_vector_type(8))) _Float16 f16x8;
typedef __attribute__((ext_vector_type(2))) _Float16 f16x2;
typedef __attribute__((ext_vector_type(4))) float f32x4;

// ============================ MFMA fused kernel v14 ============================
// v14 vs v13 (37.6 µs, best):
//  1. L1 stages 8KB (2 chunks) per 2 MFMA steps: barriers 16 -> 8, and each
//     stage's global-load latency window doubles (full 8-MFMA step before the
//     ds_write consumes the data).
//  2. __launch_bounds__(256,3): VGPR cap ~168 so 3 blocks/CU (3x51200 <= 160KB
//     LDS) actually co-reside -- a 3rd block fills the barrier-drain windows.
//  Everything else identical to v13 (T14 W-staging, K=256 bias fold, 288-block
//  combine_w).

#define TPB 256
#define BM  128
#define HSTRIDE 272                    // 128 cols x 2B + 16B pad
#define W_OFF   34816                  // H bytes
#define LDS_TOT (34816 + 16384)        // 51200 B -> 3 blocks/CU

__global__ __launch_bounds__(TPB, 3) void kan_mfma_kernel(
    const float* __restrict__ x, const _Float16* __restrict__ W0t,
    const _Float16* __restrict__ W1t, const float* __restrict__ bias0,
    const float* __restrict__ bias1, float* __restrict__ out)
{
    __shared__ char smem[LDS_TOT];
    const int tid  = threadIdx.x;
    const int lane = tid & 63;
    const int wid  = tid >> 6;          // 4 waves, disjoint 32-row strips
    const int gq   = lane >> 4;         // k-group 0..3
    const int lm   = lane & 15;
    const int wavebase = wid * 32;
    const long rowbase = (long)blockIdx.x * BM;

#if __has_builtin(__builtin_amdgcn_cvt_pkrtz)
    auto pk2 = [](float a, float b) -> f16x2 {
        return (f16x2)__builtin_amdgcn_cvt_pkrtz(a, b);
    };
#else
    auto pk2 = [](float a, float b) -> f16x2 {
        return f16x2{(_Float16)a, (_Float16)b};
    };
#endif
#if __has_builtin(__builtin_amdgcn_rcpf)
    auto frcp = [](float a) -> float { return __builtin_amdgcn_rcpf(a); };
#else
    auto frcp = [](float a) -> float { return 1.0f / a; };
#endif

    // features for 8 values -> 4 fragments {base, gi, s1, s1*gi}
    auto buildFeats4 = [&](const float* v, f16x8* dst) {
        union U { f16x8 v8; f16x2 h2[4]; } u0, u1, u2, u3;
        #pragma unroll
        for (int q = 0; q < 4; ++q) {
            float va = v[2 * q], vb = v[2 * q + 1];
            float ba = va * frcp(1.0f + __expf(-va));
            float bb = vb * frcp(1.0f + __expf(-vb));
            float ga = fminf(fmaxf(va, -1.f), 1.f) + 1.f;   // [0,2]
            float gb = fminf(fmaxf(vb, -1.f), 1.f) + 1.f;
            float s1a = (ga >= 1.f) ? 1.f : 0.f;
            float s1b = (gb >= 1.f) ? 1.f : 0.f;
            float sga = (ga >= 1.f) ? ga : 0.f;
            float sgb = (gb >= 1.f) ? gb : 0.f;
            u0.h2[q] = pk2(ba, bb);
            u1.h2[q] = pk2(ga, gb);
            u2.h2[q] = pk2(s1a, s1b);
            u3.h2[q] = pk2(sga, sgb);
        }
        dst[0] = u0.v8; dst[1] = u1.v8; dst[2] = u2.v8; dst[3] = u3.v8;
    };

    // ---------------- bias fragments (per-column, fp32) ----------------
    float b0v[8], b1v[4];
    #pragma unroll
    for (int nf = 0; nf < 8; ++nf) b0v[nf] = bias0[nf * 16 + lm];
    #pragma unroll
    for (int nf = 0; nf < 4; ++nf) b1v[nf] = bias1[nf * 16 + lm];

    // ---------------- load x values for both i-halves ----------------
    float v0[2][8], v1[2][8];           // [mi][e]: ih=0 (i=gq*8..), ih=1 (i=32+gq*8..)
    #pragma unroll
    for (int mi = 0; mi < 2; ++mi) {
        const float* xp = x + (rowbase + wavebase + mi * 16 + lm) * 64 + gq * 8;
        float4 a0 = *(const float4*)(xp);
        float4 a1 = *(const float4*)(xp + 4);
        float4 a2 = *(const float4*)(xp + 32);
        float4 a3 = *(const float4*)(xp + 36);
        v0[mi][0]=a0.x; v0[mi][1]=a0.y; v0[mi][2]=a0.z; v0[mi][3]=a0.w;
        v0[mi][4]=a1.x; v0[mi][5]=a1.y; v0[mi][6]=a1.z; v0[mi][7]=a1.w;
        v1[mi][0]=a2.x; v1[mi][1]=a2.y; v1[mi][2]=a2.z; v1[mi][3]=a2.w;
        v1[mi][4]=a3.x; v1[mi][5]=a3.y; v1[mi][6]=a3.z; v1[mi][7]=a3.w;
    }

    // ---------------- layer 0: 8 steps, W staged 8KB/step through LDS ----------------
    f32x4 acc[2][8] = {};
    {
        const char* w0 = (const char*)W0t;
        const int lb0 = (gq * 128 + lm) * 16;    // + nf*256 within chunk

        // prologue: stage chunk 0
        {
            float4 pa = *(const float4*)(w0 + tid * 32);
            float4 pb = *(const float4*)(w0 + tid * 32 + 16);
            *(float4*)(smem + W_OFF + tid * 32)      = pa;
            *(float4*)(smem + W_OFF + tid * 32 + 16) = pb;
        }
        f16x8 fr[2][4];
        buildFeats4(v0[0], fr[0]);
        buildFeats4(v0[1], fr[1]);
        __syncthreads();

        float4 wr0, wr1;
#define L0_STEP(S, C) do {                                                    \
        if ((S) < 7) {                                                        \
            wr0 = *(const float4*)(w0 + ((S) + 1) * 8192 + tid * 32);         \
            wr1 = *(const float4*)(w0 + ((S) + 1) * 8192 + tid * 32 + 16);    \
        }                                                                     \
        const char* wb = smem + W_OFF + ((S) & 1) * 8192;                     \
        f16x8 bt[8];                                                          \
        _Pragma("unroll")                                                     \
        for (int nf = 0; nf < 8; ++nf)                                        \
            bt[nf] = *(const f16x8*)(wb + lb0 + nf * 256);                    \
        _Pragma("unroll")                                                     \
        for (int mi = 0; mi < 2; ++mi) {                                      \
            f16x8 a = fr[mi][C];                                              \
            _Pragma("unroll")                                                 \
            for (int nf = 0; nf < 8; ++nf)                                    \
                acc[mi][nf] = __builtin_amdgcn_mfma_f32_16x16x32_f16(         \
                    a, bt[nf], acc[mi][nf], 0, 0, 0);                         \
        }                                                                     \
        if ((S) < 7) {                                                        \
            char* nb = smem + W_OFF + (((S) + 1) & 1) * 8192;                 \
            *(float4*)(nb + tid * 32)      = wr0;                             \
            *(float4*)(nb + tid * 32 + 16) = wr1;                             \
        }                                                                     \
        __syncthreads();                                                      \
    } while (0)

        L0_STEP(0, 0); L0_STEP(1, 1); L0_STEP(2, 2); L0_STEP(3, 3);
        buildFeats4(v1[0], fr[0]);
        buildFeats4(v1[1], fr[1]);
        L0_STEP(4, 0); L0_STEP(5, 1); L0_STEP(6, 2); L0_STEP(7, 3);
#undef L0_STEP
    }

    // h + bias0 -> H LDS f16 ; stage L1 stage0 (8KB = chunks 0,1), loads early
    {
        const char* w1g = (const char*)W1t;
        float4 p0 = *(const float4*)(w1g + tid * 32);
        float4 p1 = *(const float4*)(w1g + tid * 32 + 16);
        #pragma unroll
        for (int mi = 0; mi < 2; ++mi)
            #pragma unroll
            for (int nf = 0; nf < 8; ++nf)
                #pragma unroll
                for (int rg = 0; rg < 4; ++rg)
                    *(_Float16*)(smem + (wavebase + mi * 16 + gq * 4 + rg) * HSTRIDE
                                 + (nf * 16 + lm) * 2) = (_Float16)(acc[mi][nf][rg] + b0v[nf]);
        __syncthreads();                 // H visible; L0 W-buffer reads all done
        *(float4*)(smem + W_OFF + tid * 32)      = p0;
        *(float4*)(smem + W_OFF + tid * 32 + 16) = p1;
        __syncthreads();                 // L1 stage0 staged
    }

    // ---------------- layer 1: 8 stages x 2 steps, 8KB/stage ----------------
    f32x4 accO[2][4] = {};
    {
        const char* w1 = (const char*)W1t;
        const int lb1 = (gq * 64 + lm) * 16;     // + nf*256 within 4KB chunk
        f16x8 fr[2][4];
        float4 wr0, wr1;

#define L1_SUB(BUFOFF, C) do {                                                \
        const char* wb = smem + W_OFF + (BUFOFF);                             \
        f16x8 bt[4];                                                          \
        _Pragma("unroll")                                                     \
        for (int nf = 0; nf < 4; ++nf)                                        \
            bt[nf] = *(const f16x8*)(wb + lb1 + nf * 256);                    \
        _Pragma("unroll")                                                     \
        for (int mi = 0; mi < 2; ++mi) {                                      \
            f16x8 a = fr[mi][C];                                              \
            _Pragma("unroll")                                                 \
            for (int nf = 0; nf < 4; ++nf)                                    \
                accO[mi][nf] = __builtin_amdgcn_mfma_f32_16x16x32_f16(        \
                    a, bt[nf], accO[mi][nf], 0, 0, 0);                        \
        }                                                                     \
    } while (0)

#define L1_STAGE(SG, C0, C1) do {                                             \
        if ((SG) < 7) {                                                       \
            wr0 = *(const float4*)(w1 + ((SG) + 1) * 8192 + tid * 32);        \
            wr1 = *(const float4*)(w1 + ((SG) + 1) * 8192 + tid * 32 + 16);   \
        }                                                                     \
        L1_SUB(((SG) & 1) * 8192, C0);                                        \
        L1_SUB(((SG) & 1) * 8192 + 4096, C1);                                 \
        if ((SG) < 7) {                                                       \
            char* nb = smem + W_OFF + (((SG) + 1) & 1) * 8192;                \
            *(float4*)(nb + tid * 32)      = wr0;                             \
            *(float4*)(nb + tid * 32 + 16) = wr1;                             \
        }                                                                     \
        __syncthreads();                                                      \
    } while (0)

#define L1_FEATS(HALF, IH) do {                                               \
        _Pragma("unroll")                                                     \
        for (int mi = 0; mi < 2; ++mi) {                                      \
            const char* hrow = smem + (wavebase + mi * 16 + lm) * HSTRIDE;    \
            f16x8 hv = *(const f16x8*)(hrow + ((HALF) * 64 + (IH) * 32 + gq * 8) * 2); \
            float v[8];                                                       \
            _Pragma("unroll")                                                 \
            for (int e = 0; e < 8; ++e) v[e] = (float)hv[e];                  \
            buildFeats4(v, fr[mi]);                                           \
        }                                                                     \
    } while (0)

        L1_FEATS(0, 0);
        L1_STAGE(0, 0, 1); L1_STAGE(1, 2, 3);
        L1_FEATS(0, 1);
        L1_STAGE(2, 0, 1); L1_STAGE(3, 2, 3);
        L1_FEATS(1, 0);
        L1_STAGE(4, 0, 1); L1_STAGE(5, 2, 3);
        L1_FEATS(1, 1);
        L1_STAGE(6, 0, 1); L1_STAGE(7, 2, 3);
#undef L1_SUB
#undef L1_STAGE
#undef L1_FEATS
    }

    // ---------------- store out (+bias1) ----------------
    float* og = out + (rowbase + wavebase) * 64;
    #pragma unroll
    for (int mi = 0; mi < 2; ++mi)
        #pragma unroll
        for (int nf = 0; nf < 4; ++nf)
            #pragma unroll
            for (int rg = 0; rg < 4; ++rg)
                og[(mi * 16 + gq * 4 + rg) * 64 + nf * 16 + lm] = accO[mi][nf][rg] + b1v[nf];
}

// ------------- pre-kernel: fold weights + wide-parallel bias (= v13) -------------
// blocks 0..255: weight fold.  blocks 256..271: bias0 (16 blk x 8 cols, 2-iter).
// blocks 272..287: bias1 (16 blk x 4 cols, 2-iter).
// Feature order q: {base, gi, s1, s1*gi}.  Per edge:
//   P0 = cp.bv0 ; Q0 = cp.(bv1-bv0) ; P1 = cp.(2bv1-bv2) ; Q1 = cp.(bv2-bv1)
//   w = imp * {bw, sw*Q0, sw*(P1-P0), sw*(Q1-Q0)};  bias_j = sum_i imp*sw*P0
// W0t flat f = ((s*4+g)*128+n)*8+e ; s=ih*4+q ; i=ih*32+g*8+e ; edge=i*128+n
// W1t flat f = (((half*8+s)*4+g)*64+n)*8+e ; i2=half*64+ih*32+g*8+e
__global__ __launch_bounds__(256) void kan_combine_w(
    const float* __restrict__ cp0, const float* __restrict__ bw0,
    const float* __restrict__ sw0, const float* __restrict__ imp0,
    const float* __restrict__ cp1, const float* __restrict__ bw1,
    const float* __restrict__ sw1, const float* __restrict__ imp1,
    _Float16* __restrict__ W0t, _Float16* __restrict__ W1t,
    float* __restrict__ bias0, float* __restrict__ bias1)
{
    float bvv[3][5];
    #pragma unroll
    for (int g = 0; g < 3; ++g) {
        float gv = (float)g - 1.0f;
        float e[5]; float s = 0.f;
        #pragma unroll
        for (int i = 0; i < 5; ++i) {
            float cc = -0.8125f + 0.325f * (float)i;
            float d  = (gv - cc) * (1.0f / 0.65f);
            e[i] = __expf(-d * d); s += e[i];
        }
        float inv = 1.0f / (s + 1e-6f);
        #pragma unroll
        for (int i = 0; i < 5; ++i) bvv[g][i] = e[i] * inv;
    }

    auto wval = [&](const float* cp, float bw, float sw, float imp, int q) -> float {
        if (q == 0) return imp * bw;
        float P0 = 0.f, Q0 = 0.f, P1 = 0.f, Q1 = 0.f;
        #pragma unroll
        for (int c = 0; c < 5; ++c) {
            P0 += cp[c] * bvv[0][c];
            Q0 += cp[c] * (bvv[1][c] - bvv[0][c]);
            P1 += cp[c] * (2.f * bvv[1][c] - bvv[2][c]);
            Q1 += cp[c] * (bvv[2][c] - bvv[1][c]);
        }
        float r = (q == 1) ? Q0 : (q == 2) ? (P1 - P0) : (Q1 - Q0);
        return imp * sw * r;
    };
    auto p0val = [&](const float* cp) -> float {
        float P0 = 0.f;
        #pragma unroll
        for (int c = 0; c < 5; ++c) P0 += cp[c] * bvv[0][c];
        return P0;
    };

    const int bx = blockIdx.x;
    const int t  = threadIdx.x;

    if (bx < 256) {
        int f = bx * 256 + t;
        if (f < 32768) {
            int e = f & 7, n = (f >> 3) & 127, g = (f >> 10) & 3, s = f >> 12;
            int ih = s >> 2, q = s & 3;
            int i = ih * 32 + g * 8 + e;
            int edge = i * 128 + n;
            W0t[f] = (_Float16)wval(cp0 + edge * 5, bw0[edge], sw0[edge], imp0[edge], q);
        } else {
            int f2 = f - 32768;
            int e = f2 & 7, n = (f2 >> 3) & 63, g = (f2 >> 9) & 3;
            int tq = f2 >> 11;
            int half = tq >> 3, s = tq & 7;
            int ih = s >> 2, q = s & 3;
            int i2 = half * 64 + ih * 32 + g * 8 + e;
            int edge = i2 * 64 + n;
            W1t[f2] = (_Float16)wval(cp1 + edge * 5, bw1[edge], sw1[edge], imp1[edge], q);
        }
    } else if (bx < 272) {
        __shared__ float part[256];
        int bb = bx - 256;
        int jj = t >> 5, split = t & 31;
        int j = bb * 8 + jj;
        float s = 0.f;
        #pragma unroll
        for (int k = 0; k < 2; ++k) {
            int i = split * 2 + k;
            int edge = i * 128 + j;
            s += imp0[edge] * sw0[edge] * p0val(cp0 + edge * 5);
        }
        part[t] = s;
        __syncthreads();
        if (t < 8) {
            float acc = 0.f;
            #pragma unroll
            for (int k = 0; k < 32; ++k) acc += part[t * 32 + k];
            bias0[bb * 8 + t] = acc;
        }
    } else {
        __shared__ float part[256];
        int bb = bx - 272;
        int jj = t >> 6, split = t & 63;
        int j = bb * 4 + jj;
        float s = 0.f;
        #pragma unroll
        for (int k = 0; k < 2; ++k) {
            int i2 = split * 2 + k;
            int edge = i2 * 64 + j;
            s += imp1[edge] * sw1[edge] * p0val(cp1 + edge * 5);
        }
        part[t] = s;
        __syncthreads();
        if (t < 4) {
            float acc = 0.f;
            #pragma unroll
            for (int k = 0; k < 64; ++k) acc += part[t * 64 + k];
            bias1[bb * 4 + t] = acc;
        }
    }
}

// ===================== fallback: proven fp32 kernel (round 2) =====================
#define NTHR 256
#define JT 32
#define WS8 8

#define STAGE_L0(JBASE) do {                                                  \
    _Pragma("unroll")                                                         \
    for (int p = 0; p < 8; ++p) {                                             \
        int idx = tid + p * NTHR;                                             \
        int i  = idx >> 5;                                                    \
        int jj = idx & 31;                                                    \
        int e  = i * 128 + (JBASE) + jj;                                      \
        float im = imp0[e];                                                   \
        float wb = bw0[e] * im;                                               \
        float ws = sw0[e] * im;                                               \
        const float* cp = cp0 + e * 5;                                        \
        float* wp = wbuf + idx * WS8;                                         \
        wp[0] = wb;                                                           \
        wp[1] = ws * cp[0]; wp[2] = ws * cp[1]; wp[3] = ws * cp[2];           \
        wp[4] = ws * cp[3]; wp[5] = ws * cp[4];                               \
    }                                                                         \
} while (0)

#define STAGE_L1(IBASE, JBASE) do {                                           \
    _Pragma("unroll")                                                         \
    for (int p = 0; p < 8; ++p) {                                             \
        int idx = tid + p * NTHR;                                             \
        int ii = idx >> 5;                                                    \
        int jj = idx & 31;                                                    \
        int e  = ((IBASE) + ii) * 64 + (JBASE) + jj;                          \
        float im = imp1[e];                                                   \
        float wb = bw1[e] * im;                                               \
        float ws = sw1[e] * im;                                               \
        const float* cp = cp1 + e * 5;                                        \
        float* wp = wbuf + idx * WS8;                                         \
        wp[0] = wb;                                                           \
        wp[1] = ws * cp[0]; wp[2] = ws * cp[1]; wp[3] = ws * cp[2];           \
        wp[4] = ws * cp[3]; wp[5] = ws * cp[4];                               \
    }                                                                         \
} while (0)

#define COMPUTE_TILE(ACC) do {                                                \
    _Pragma("unroll 2")                                                       \
    for (int i = 0; i < 64; ++i) {                                            \
        float v  = vbuf[i][tid];                                              \
        float sg = 1.0f / (1.0f + __expf(-v));                                \
        float base = v * sg;                                                  \
        float xc = fminf(fmaxf(v, -1.0f), 1.0f);                              \
        float gi = xc + 1.0f;                                                 \
        int lo = (int)gi; lo = (lo > 2) ? 2 : lo;                             \
        float fr = gi - (float)lo;                                            \
        int hi = (fr > 0.0f) ? (lo + 1) : lo;                                 \
        float b0 = bvt[lo][0]; b0 += (bvt[hi][0] - b0) * fr;                  \
        float b1 = bvt[lo][1]; b1 += (bvt[hi][1] - b1) * fr;                  \
        float b2 = bvt[lo][2]; b2 += (bvt[hi][2] - b2) * fr;                  \
        float b3 = bvt[lo][3]; b3 += (bvt[hi][3] - b3) * fr;                  \
        float b4 = bvt[lo][4]; b4 += (bvt[hi][4] - b4) * fr;                  \
        const float* wr = wbuf + i * (JT * WS8);                              \
        _Pragma("unroll")                                                     \
        for (int jj = 0; jj < JT; ++jj) {                                     \
            const float* wp = wr + jj * WS8;                                  \
            float a = ACC[jj];                                                \
            a = fmaf(wp[0], base, a);                                         \
            a = fmaf(wp[1], b0, a);                                           \
            a = fmaf(wp[2], b1, a);                                           \
            a = fmaf(wp[3], b2, a);                                           \
            a = fmaf(wp[4], b3, a);                                           \
            a = fmaf(wp[5], b4, a);                                           \
            ACC[jj] = a;                                                      \
        }                                                                     \
    }                                                                         \
} while (0)

__global__ __launch_bounds__(NTHR) void kan_fused_kernel(
    const float* __restrict__ x,
    const float* __restrict__ cp0, const float* __restrict__ bw0,
    const float* __restrict__ sw0, const float* __restrict__ imp0,
    const float* __restrict__ cp1, const float* __restrict__ bw1,
    const float* __restrict__ sw1, const float* __restrict__ imp1,
    float* __restrict__ out)
{
    __shared__ float vbuf[64][NTHR + 1];
    __shared__ float wbuf[64 * JT * WS8];
    __shared__ float bvt[3][8];

    const int tid = threadIdx.x;

    if (tid < 3) {
        float gv = -1.0f + (float)tid;
        float e[5];
        float s = 0.0f;
        #pragma unroll
        for (int i = 0; i < 5; ++i) {
            float c = -0.8125f + 0.325f * (float)i;
            float d = (gv - c) * (1.0f / 0.65f);
            e[i] = expf(-d * d);
            s += e[i];
        }
        float inv = 1.0f / (s + 1e-6f);
        #pragma unroll
        for (int i = 0; i < 5; ++i) bvt[tid][i] = e[i] * inv;
    }

    {
        const float4* xg = (const float4*)(x + (size_t)blockIdx.x * (NTHR * 64));
        #pragma unroll
        for (int it = 0; it < 16; ++it) {
            int e4 = tid + it * NTHR;
            float4 v = xg[e4];
            int r  = e4 >> 4;
            int ib = (e4 & 15) << 2;
            vbuf[ib + 0][r] = v.x;
            vbuf[ib + 1][r] = v.y;
            vbuf[ib + 2][r] = v.z;
            vbuf[ib + 3][r] = v.w;
        }
    }
    __syncthreads();

    float h0[32] = {}, h1[32] = {}, h2[32] = {}, h3[32] = {};
    STAGE_L0(0);   __syncthreads(); COMPUTE_TILE(h0); __syncthreads();
    STAGE_L0(32);  __syncthreads(); COMPUTE_TILE(h1); __syncthreads();
    STAGE_L0(64);  __syncthreads(); COMPUTE_TILE(h2); __syncthreads();
    STAGE_L0(96);  __syncthreads(); COMPUTE_TILE(h3); __syncthreads();

    #pragma unroll
    for (int i = 0; i < 32; ++i) vbuf[i][tid] = h0[i];
    #pragma unroll
    for (int i = 0; i < 32; ++i) vbuf[32 + i][tid] = h1[i];

    float o0[32] = {}, o1[32] = {};
    STAGE_L1(0, 0);   __syncthreads(); COMPUTE_TILE(o0); __syncthreads();
    STAGE_L1(0, 32);  __syncthreads(); COMPUTE_TILE(o1); __syncthreads();

    #pragma unroll
    for (int i = 0; i < 32; ++i) vbuf[i][tid] = h2[i];
    #pragma unroll
    for (int i = 0; i < 32; ++i) vbuf[32 + i][tid] = h3[i];

    STAGE_L1(64, 0);  __syncthreads(); COMPUTE_TILE(o0); __syncthreads();
    STAGE_L1(64, 32); __syncthreads(); COMPUTE_TILE(o1);

    float4* og = (float4*)(out + (size_t)blockIdx.x * (NTHR * 64) + (size_t)tid * 64);
    #pragma unroll
    for (int q = 0; q < 8; ++q)
        og[q] = make_float4(o0[4 * q + 0], o0[4 * q + 1], o0[4 * q + 2], o0[4 * q + 3]);
    #pragma unroll
    for (int q = 0; q < 8; ++q)
        og[8 + q] = make_float4(o1[4 * q + 0], o1[4 * q + 1], o1[4 * q + 2], o1[4 * q + 3]);
}

// =================================== launch ===================================
extern "C" void kernel_launch(void* const* d_in, const int* in_sizes, int n_in,
                              void* d_out, int out_size, void* d_ws, size_t ws_size,
                              hipStream_t stream) {
    const float* x    = (const float*)d_in[0];
    const float* cp0  = (const float*)d_in[1];
    const float* bw0  = (const float*)d_in[2];
    const float* sw0  = (const float*)d_in[3];
    const float* imp0 = (const float*)d_in[4];
    const float* cp1  = (const float*)d_in[5];
    const float* bw1  = (const float*)d_in[6];
    const float* sw1  = (const float*)d_in[7];
    const float* imp1 = (const float*)d_in[8];
    float* out = (float*)d_out;

    const int B = in_sizes[0] / 64;                 // 131072
    const size_t need = 65536 * sizeof(_Float16) + 192 * sizeof(float);

    if (ws_size >= need && (B % BM) == 0) {
        _Float16* W0t = (_Float16*)d_ws;
        _Float16* W1t = W0t + 32768;
        float* bias0 = (float*)(W1t + 32768);
        float* bias1 = bias0 + 128;
        kan_combine_w<<<288, 256, 0, stream>>>(cp0, bw0, sw0, imp0,
                                               cp1, bw1, sw1, imp1,
                                               W0t, W1t, bias0, bias1);
        kan_mfma_kernel<<<B / BM, TPB, 0, stream>>>(x, W0t, W1t, bias0, bias1, out);
    } else {
        kan_fused_kernel<<<B / NTHR, NTHR, 0, stream>>>(
            x, cp0, bw0, sw0, imp0, cp1, bw1, sw1, imp1, out);
    }
}